// Round 1
// baseline (301.468 us; speedup 1.0000x reference)
//
#include <hip/hip_runtime.h>

typedef float f32x4 __attribute__((ext_vector_type(4)));
typedef float f32x16 __attribute__((ext_vector_type(16)));
typedef short s16x4 __attribute__((ext_vector_type(4)));
typedef unsigned int u32x4 __attribute__((ext_vector_type(4)));

__device__ __forceinline__ unsigned f2bf(float f) {
    unsigned u = __builtin_bit_cast(unsigned, f);
    u += 0x7FFFu + ((u >> 16) & 1u);   // round-to-nearest-even
    return u >> 16;
}

__device__ __forceinline__ s16x4 pack4(float a, float b, float c, float d) {
    s16x4 r;
    r[0] = (short)f2bf(a);
    r[1] = (short)f2bf(b);
    r[2] = (short)f2bf(c);
    r[3] = (short)f2bf(d);
    return r;
}

// ---------------------------------------------------------------------------
// Node kernel: y = relu(relu(x@W1^T+b1)@W2^T+b2) @ Wm^T   (Wm row stride 96)
// Output stored as bf16 [N,32].
// ---------------------------------------------------------------------------
__global__ __launch_bounds__(256) void node_kernel(
    const float* __restrict__ X,
    const float* __restrict__ W1, const float* __restrict__ b1,
    const float* __restrict__ W2, const float* __restrict__ b2,
    const float* __restrict__ Wm,          // = We1 + 32 (var) or +64 (con)
    unsigned short* __restrict__ outp, int N)
{
    int i = blockIdx.x * blockDim.x + threadIdx.x;
    if (i >= N) return;

    float x[32], a[32];
    const f32x4* Xr = reinterpret_cast<const f32x4*>(X + (size_t)i * 32);
#pragma unroll
    for (int q = 0; q < 8; ++q) {
        f32x4 v = Xr[q];
        x[4*q+0] = v[0]; x[4*q+1] = v[1]; x[4*q+2] = v[2]; x[4*q+3] = v[3];
    }
#pragma unroll
    for (int j = 0; j < 32; ++j) {
        float s = b1[j];
#pragma unroll
        for (int k = 0; k < 32; ++k) s = fmaf(x[k], W1[j*32+k], s);
        a[j] = fmaxf(s, 0.f);
    }
#pragma unroll
    for (int j = 0; j < 32; ++j) {
        float s = b2[j];
#pragma unroll
        for (int k = 0; k < 32; ++k) s = fmaf(a[k], W2[j*32+k], s);
        x[j] = fmaxf(s, 0.f);              // reuse x[] as the compressed node feature
    }
    unsigned uw[16];
#pragma unroll
    for (int j = 0; j < 32; j += 2) {
        float s0 = 0.f, s1 = 0.f;
#pragma unroll
        for (int k = 0; k < 32; ++k) {
            s0 = fmaf(x[k], Wm[j*96 + k], s0);
            s1 = fmaf(x[k], Wm[(j+1)*96 + k], s1);
        }
        uw[j >> 1] = f2bf(s0) | (f2bf(s1) << 16);
    }
    u32x4* orow = reinterpret_cast<u32x4*>(outp + (size_t)i * 32);
#pragma unroll
    for (int q = 0; q < 4; ++q) {
        u32x4 v;
        v[0] = uw[4*q+0]; v[1] = uw[4*q+1]; v[2] = uw[4*q+2]; v[3] = uw[4*q+3];
        orow[q] = v;
    }
}

// ---------------------------------------------------------------------------
// Edge kernel. One wave handles a 32-edge tile.
// Layer1 (K=96 via 12 mfma_32x32x8):  T^T = [W1e | I | I] · [E | pv[i0] | pc[i1]]^T,
// acc preloaded with be1. D-layout: lane=32g+n holds T[e=n][ch=(r&3)+8(r>>2)+4g].
// With K=8 MFMAs, D r-quads line up exactly with B-fragment k-groups, so
// relu+bf16-pack feeds layer2 with zero cross-lane shuffles.
// ---------------------------------------------------------------------------
__global__ __launch_bounds__(256, 3) void edge_kernel(
    const float* __restrict__ Ef, const int* __restrict__ idx,
    const unsigned short* __restrict__ pv, const unsigned short* __restrict__ pc,
    const float* __restrict__ We1, const float* __restrict__ be1,
    const float* __restrict__ We2, const float* __restrict__ be2,
    float* __restrict__ out, int nE)
{
    const int lane = threadIdx.x & 63;
    const int g = lane >> 5;       // half-wave
    const int m = lane & 31;       // A-fragment row (out channel) == B/D edge slot

    // A fragments, hoisted: layer1 edge part  A[m][8q+4g+j] = We1[m][8q+4g+j]
    s16x4 aW1[4], aW2[4], aI[4];
#pragma unroll
    for (int q = 0; q < 4; ++q) {
        const float* p = We1 + m * 96 + 8*q + 4*g;
        aW1[q] = pack4(p[0], p[1], p[2], p[3]);
        const float* p2 = We2 + m * 32 + 8*q + 4*g;
        aW2[q] = pack4(p2[0], p2[1], p2[2], p2[3]);
        s16x4 r;
#pragma unroll
        for (int j = 0; j < 4; ++j) r[j] = (short)((8*q + 4*g + j == m) ? 0x3F80 : 0);
        aI[q] = r;
    }
    // bias fragments in verified C/D layout: ch = (r&3) + 8*(r>>2) + 4*g
    f32x16 bias1, bias2;
#pragma unroll
    for (int r = 0; r < 16; ++r) {
        int ch = (r & 3) + 8 * (r >> 2) + 4 * g;
        bias1[r] = be1[ch];
        bias2[r] = be2[ch];
    }

    const int tiles = nE >> 5;
    const int nw = (gridDim.x * blockDim.x) >> 6;
    int w = (blockIdx.x * blockDim.x + threadIdx.x) >> 6;

    for (; w < tiles; w += nw) {
        const int eg = (w << 5) + m;           // this lane's edge (B/D col slot)
        const int i0 = idx[eg];
        const int i1 = idx[nE + eg];

        // B fragments: edge features (f32 -> bf16)
        const float* Er = Ef + (size_t)eg * 32 + 4*g;
        s16x4 bE[4];
#pragma unroll
        for (int q = 0; q < 4; ++q) {
            f32x4 v = *reinterpret_cast<const f32x4*>(Er + 8*q);
            bE[q] = pack4(v[0], v[1], v[2], v[3]);
        }
        // B fragments: gathered node partials (already bf16)
        const unsigned short* pvr = pv + (size_t)i0 * 32 + 4*g;
        const unsigned short* pcr = pc + (size_t)i1 * 32 + 4*g;
        s16x4 bV[4], bC[4];
#pragma unroll
        for (int q = 0; q < 4; ++q) {
            bV[q] = *reinterpret_cast<const s16x4*>(pvr + 8*q);
            bC[q] = *reinterpret_cast<const s16x4*>(pcr + 8*q);
        }

        f32x16 acc = bias1;
#pragma unroll
        for (int q = 0; q < 4; ++q)
            acc = __builtin_amdgcn_mfma_f32_32x32x8bf16_1k(aW1[q], bE[q], acc, 0, 0, 0);
#pragma unroll
        for (int q = 0; q < 4; ++q)
            acc = __builtin_amdgcn_mfma_f32_32x32x8bf16_1k(aI[q], bV[q], acc, 0, 0, 0);
#pragma unroll
        for (int q = 0; q < 4; ++q)
            acc = __builtin_amdgcn_mfma_f32_32x32x8bf16_1k(aI[q], bC[q], acc, 0, 0, 0);

        // relu + pack: B-frag(kb) slot j is exactly h[r = 4*kb + j]
        s16x4 bH[4];
#pragma unroll
        for (int q = 0; q < 4; ++q)
            bH[q] = pack4(fmaxf(acc[4*q+0], 0.f), fmaxf(acc[4*q+1], 0.f),
                          fmaxf(acc[4*q+2], 0.f), fmaxf(acc[4*q+3], 0.f));

        f32x16 acc2 = bias2;
#pragma unroll
        for (int q = 0; q < 4; ++q)
            acc2 = __builtin_amdgcn_mfma_f32_32x32x8bf16_1k(aW2[q], bH[q], acc2, 0, 0, 0);

        float* orow = out + (size_t)eg * 32 + 4*g;
#pragma unroll
        for (int q = 0; q < 4; ++q) {
            f32x4 vv;
            vv[0] = acc2[4*q+0]; vv[1] = acc2[4*q+1];
            vv[2] = acc2[4*q+2]; vv[3] = acc2[4*q+3];
            *reinterpret_cast<f32x4*>(orow + 8*q) = vv;
        }
    }
}

extern "C" void kernel_launch(void* const* d_in, const int* in_sizes, int n_in,
                              void* d_out, int out_size, void* d_ws, size_t ws_size,
                              hipStream_t stream) {
    const float* var_f = (const float*)d_in[0];
    const float* con_f = (const float*)d_in[1];
    const float* Ef    = (const float*)d_in[2];
    const int*   idx   = (const int*)d_in[3];
    const float* Wv1 = (const float*)d_in[4];
    const float* bv1 = (const float*)d_in[5];
    const float* Wv2 = (const float*)d_in[6];
    const float* bv2 = (const float*)d_in[7];
    const float* Wc1 = (const float*)d_in[8];
    const float* bc1 = (const float*)d_in[9];
    const float* Wc2 = (const float*)d_in[10];
    const float* bc2 = (const float*)d_in[11];
    const float* We1 = (const float*)d_in[12];
    const float* be1 = (const float*)d_in[13];
    const float* We2 = (const float*)d_in[14];
    const float* be2 = (const float*)d_in[15];
    float* out = (float*)d_out;

    const int nV = in_sizes[0] / 32;
    const int nC = in_sizes[1] / 32;
    const int nE = in_sizes[2] / 32;

    unsigned short* pv = (unsigned short*)d_ws;
    unsigned short* pc = pv + (size_t)nV * 32;

    node_kernel<<<(nV + 255) / 256, 256, 0, stream>>>(var_f, Wv1, bv1, Wv2, bv2,
                                                      We1 + 32, pv, nV);
    node_kernel<<<(nC + 255) / 256, 256, 0, stream>>>(con_f, Wc1, bc1, Wc2, bc2,
                                                      We1 + 64, pc, nC);
    edge_kernel<<<2048, 256, 0, stream>>>(Ef, idx, pv, pc, We1, be1, We2, be2,
                                          out, nE);
}

// Round 2
// 171.820 us; speedup vs baseline: 1.7546x; 1.7546x over previous
//
#include <hip/hip_runtime.h>

typedef float  f32x2  __attribute__((ext_vector_type(2)));
typedef float  f32x4  __attribute__((ext_vector_type(4)));
typedef float  f32x16 __attribute__((ext_vector_type(16)));
typedef short  s16x4  __attribute__((ext_vector_type(4)));
typedef short  s16x8  __attribute__((ext_vector_type(8)));
typedef unsigned int u32x2 __attribute__((ext_vector_type(2)));

__device__ __forceinline__ unsigned f2bf(float f) {
    unsigned u = __builtin_bit_cast(unsigned, f);
    u += 0x7FFFu + ((u >> 16) & 1u);   // RNE
    return u >> 16;
}
__device__ __forceinline__ s16x4 pack4(float a, float b, float c, float d) {
    u32x2 u;
    u[0] = f2bf(a) | (f2bf(b) << 16);
    u[1] = f2bf(c) | (f2bf(d) << 16);
    return __builtin_bit_cast(s16x4, u);
}
__device__ __forceinline__ s16x4 lo4(s16x8 v) { return __builtin_shufflevector(v, v, 0, 1, 2, 3); }
__device__ __forceinline__ s16x4 hi4(s16x8 v) { return __builtin_shufflevector(v, v, 4, 5, 6, 7); }

// ---------------------------------------------------------------------------
// Node kernel (MFMA): P = relu(relu(X W1^T + b1) W2^T + b2) Wm^T (+ bm), bf16.
// One wave per 32-node tile; D->B chaining via verified C/D layout.
// ---------------------------------------------------------------------------
__global__ __launch_bounds__(256) void node_kernel(
    const float* __restrict__ X,
    const float* __restrict__ W1, const float* __restrict__ b1,
    const float* __restrict__ W2, const float* __restrict__ b2,
    const float* __restrict__ Wm, int wm_stride, const float* __restrict__ bm,
    unsigned short* __restrict__ outp, int N)
{
    const int lane = threadIdx.x & 63;
    const int g = lane >> 5, m = lane & 31;
    const int ntile = (N + 31) >> 5;
    const int tile = (blockIdx.x * blockDim.x + threadIdx.x) >> 6;
    if (tile >= ntile) return;

    s16x4 a1[4], a2[4], am[4];
#pragma unroll
    for (int q = 0; q < 4; ++q) {
        const float* p1 = W1 + m * 32 + 8 * q + 4 * g;
        a1[q] = pack4(p1[0], p1[1], p1[2], p1[3]);
        const float* p2 = W2 + m * 32 + 8 * q + 4 * g;
        a2[q] = pack4(p2[0], p2[1], p2[2], p2[3]);
        const float* pm = Wm + m * wm_stride + 8 * q + 4 * g;
        am[q] = pack4(pm[0], pm[1], pm[2], pm[3]);
    }
    f32x16 f1, f2, f3;
#pragma unroll
    for (int r = 0; r < 16; ++r) {
        int ch = (r & 3) + 8 * (r >> 2) + 4 * g;
        f1[r] = b1[ch];
        f2[r] = b2[ch];
        f3[r] = bm ? bm[ch] : 0.f;
    }

    const int node0 = tile * 32 + m;
    const int node = node0 < N ? node0 : N - 1;

    s16x4 bX[4];
#pragma unroll
    for (int q = 0; q < 4; ++q) {
        f32x4 v = *reinterpret_cast<const f32x4*>(X + (size_t)node * 32 + 8 * q + 4 * g);
        bX[q] = pack4(v[0], v[1], v[2], v[3]);
    }
    f32x16 acc = f1;
#pragma unroll
    for (int q = 0; q < 4; ++q) acc = __builtin_amdgcn_mfma_f32_32x32x8bf16_1k(a1[q], bX[q], acc, 0, 0, 0);
    s16x4 bH[4];
#pragma unroll
    for (int q = 0; q < 4; ++q)
        bH[q] = pack4(fmaxf(acc[4*q+0], 0.f), fmaxf(acc[4*q+1], 0.f),
                      fmaxf(acc[4*q+2], 0.f), fmaxf(acc[4*q+3], 0.f));
    acc = f2;
#pragma unroll
    for (int q = 0; q < 4; ++q) acc = __builtin_amdgcn_mfma_f32_32x32x8bf16_1k(a2[q], bH[q], acc, 0, 0, 0);
#pragma unroll
    for (int q = 0; q < 4; ++q)
        bH[q] = pack4(fmaxf(acc[4*q+0], 0.f), fmaxf(acc[4*q+1], 0.f),
                      fmaxf(acc[4*q+2], 0.f), fmaxf(acc[4*q+3], 0.f));
    acc = f3;
#pragma unroll
    for (int q = 0; q < 4; ++q) acc = __builtin_amdgcn_mfma_f32_32x32x8bf16_1k(am[q], bH[q], acc, 0, 0, 0);

    if (node0 < N) {
#pragma unroll
        for (int q = 0; q < 4; ++q) {
            s16x4 o = pack4(acc[4*q+0], acc[4*q+1], acc[4*q+2], acc[4*q+3]);
            *reinterpret_cast<s16x4*>(outp + (size_t)node0 * 32 + 8 * q + 4 * g) = o;
        }
    }
}

// ---------------------------------------------------------------------------
// Edge kernel. Block = 4 waves, 128-edge tiles, grid-stride.
// Ef staged via global_load_lds (XOR-pre-swizzled source), double-buffered.
// Layer-1 K-mapping ch=16g+4q+j  -> gathers are 2 contiguous 16B loads/matrix.
// Layer-2 K-mapping ch=8q+4g+j   -> D->B chaining, no shuffles.
// Stores transposed through LDS (stride-34 rows) -> coalesced nt stores.
// ---------------------------------------------------------------------------
__device__ __forceinline__ void stage_tile(const float* __restrict__ Ef, float* buf,
                                           int tile, int wv, int a, int b) {
    const float* src = Ef + (size_t)tile * 4096 + (size_t)(wv * 32 + a) * 32 + ((b ^ a) << 2);
    float* dst = buf + wv * 1024;
#pragma unroll
    for (int j = 0; j < 4; ++j) {
        __builtin_amdgcn_global_load_lds(
            (const __attribute__((address_space(1))) unsigned int*)(src + j * 256),
            (__attribute__((address_space(3))) unsigned int*)(dst + j * 256),
            16, 0, 0);
    }
}

__global__ __launch_bounds__(256) void edge_kernel(
    const float* __restrict__ Ef, const int* __restrict__ idx,
    const unsigned short* __restrict__ pv, const unsigned short* __restrict__ pc,
    const float* __restrict__ We1, const float* __restrict__ We2,
    const float* __restrict__ be2,
    float* __restrict__ out, int nE)
{
    __shared__ float lds[2 * 4096 + 128 * 34];
    float* ldso = lds + 8192;

    const int lane = threadIdx.x & 63;
    const int wv = threadIdx.x >> 6;
    const int g = lane >> 5, n = lane & 31;
    const int a = lane >> 3, b = lane & 7;

    // A fragments. Layer 1 uses ch1(q,g,j)=16g+4q+j; layer 2 uses 8q+4g+j.
    s16x4 aW1[4], aI[4], aW2[4];
#pragma unroll
    for (int q = 0; q < 4; ++q) {
        const float* p = We1 + n * 96 + 16 * g + 4 * q;
        aW1[q] = pack4(p[0], p[1], p[2], p[3]);
        s16x4 r;
#pragma unroll
        for (int j = 0; j < 4; ++j) r[j] = (short)((16 * g + 4 * q + j == n) ? 0x3F80 : 0);
        aI[q] = r;
        const float* p2 = We2 + n * 32 + 8 * q + 4 * g;
        aW2[q] = pack4(p2[0], p2[1], p2[2], p2[3]);
    }
    f32x16 bias2;
#pragma unroll
    for (int r = 0; r < 16; ++r) bias2[r] = be2[(r & 3) + 8 * (r >> 2) + 4 * g];

    const int tiles = nE >> 7;
    int t = blockIdx.x;
    if (t >= tiles) return;
    int cur = 0;

    stage_tile(Ef, lds, t, wv, a, b);
    int e = t * 128 + wv * 32 + n;
    int i0 = idx[e], i1 = idx[nE + e];

    while (true) {
        const int tn = t + gridDim.x;
        __syncthreads();   // BAR1: stage(cur) done; lds_out free for this iter
        if (tn < tiles) stage_tile(Ef, lds + (cur ^ 1) * 4096, tn, wv, a, b);

        // gathers: two contiguous 16B loads per matrix (this lane's half-row)
        const unsigned short* pvr = pv + (size_t)i0 * 32 + 16 * g;
        const unsigned short* pcr = pc + (size_t)i1 * 32 + 16 * g;
        s16x8 v0 = *reinterpret_cast<const s16x8*>(pvr);
        s16x8 v1 = *reinterpret_cast<const s16x8*>(pvr + 8);
        s16x8 c0 = *reinterpret_cast<const s16x8*>(pcr);
        s16x8 c1 = *reinterpret_cast<const s16x8*>(pcr + 8);

        // prefetch next tile's indices
        int i0n = 0, i1n = 0;
        if (tn < tiles) {
            int en = tn * 128 + wv * 32 + n;
            i0n = idx[en];
            i1n = idx[nE + en];
        }

        // B fragments of Ef from LDS (swizzled read)
        const float* efb = lds + cur * 4096 + (size_t)(wv * 32 + n) * 32;
        f32x16 acc = {};
        s16x4 bE[4];
#pragma unroll
        for (int q = 0; q < 4; ++q) {
            f32x4 v = *reinterpret_cast<const f32x4*>(efb + (((4 * g + q) ^ (n & 7)) << 2));
            bE[q] = pack4(v[0], v[1], v[2], v[3]);
        }
#pragma unroll
        for (int q = 0; q < 4; ++q) acc = __builtin_amdgcn_mfma_f32_32x32x8bf16_1k(aW1[q], bE[q], acc, 0, 0, 0);
        acc = __builtin_amdgcn_mfma_f32_32x32x8bf16_1k(aI[0], lo4(v0), acc, 0, 0, 0);
        acc = __builtin_amdgcn_mfma_f32_32x32x8bf16_1k(aI[1], hi4(v0), acc, 0, 0, 0);
        acc = __builtin_amdgcn_mfma_f32_32x32x8bf16_1k(aI[2], lo4(v1), acc, 0, 0, 0);
        acc = __builtin_amdgcn_mfma_f32_32x32x8bf16_1k(aI[3], hi4(v1), acc, 0, 0, 0);
        acc = __builtin_amdgcn_mfma_f32_32x32x8bf16_1k(aI[0], lo4(c0), acc, 0, 0, 0);
        acc = __builtin_amdgcn_mfma_f32_32x32x8bf16_1k(aI[1], hi4(c0), acc, 0, 0, 0);
        acc = __builtin_amdgcn_mfma_f32_32x32x8bf16_1k(aI[2], lo4(c1), acc, 0, 0, 0);
        acc = __builtin_amdgcn_mfma_f32_32x32x8bf16_1k(aI[3], hi4(c1), acc, 0, 0, 0);

        // relu + pack (D layout -> layer-2 B frags)
        s16x4 bH[4];
#pragma unroll
        for (int q = 0; q < 4; ++q)
            bH[q] = pack4(fmaxf(acc[4*q+0], 0.f), fmaxf(acc[4*q+1], 0.f),
                          fmaxf(acc[4*q+2], 0.f), fmaxf(acc[4*q+3], 0.f));
        f32x16 acc2 = bias2;
#pragma unroll
        for (int q = 0; q < 4; ++q) acc2 = __builtin_amdgcn_mfma_f32_32x32x8bf16_1k(aW2[q], bH[q], acc2, 0, 0, 0);

        // phase 3: stage result into LDS [row][ch], row stride 34 words
        {
            float* orow = ldso + (size_t)(wv * 32 + n) * 34;
#pragma unroll
            for (int q = 0; q < 4; ++q) {
                f32x2 lo; lo[0] = acc2[4*q+0]; lo[1] = acc2[4*q+1];
                f32x2 hi; hi[0] = acc2[4*q+2]; hi[1] = acc2[4*q+3];
                *reinterpret_cast<f32x2*>(orow + 8 * q + 4 * g)     = lo;
                *reinterpret_cast<f32x2*>(orow + 8 * q + 4 * g + 2) = hi;
            }
        }
        __syncthreads();   // BAR2: lds_out populated; stage(next) drained

        // phase 4: coalesced non-temporal store
        {
            const int T = threadIdx.x;
            const size_t obase = (size_t)t * 4096;
#pragma unroll
            for (int p = 0; p < 4; ++p) {
                int w = p * 1024 + T * 4;
                int row = w >> 5, col = w & 31;
                const float* s = ldso + (size_t)row * 34 + col;
                f32x2 lo = *reinterpret_cast<const f32x2*>(s);
                f32x2 hi = *reinterpret_cast<const f32x2*>(s + 2);
                f32x4 v; v[0] = lo[0]; v[1] = lo[1]; v[2] = hi[0]; v[3] = hi[1];
                __builtin_nontemporal_store(v, reinterpret_cast<f32x4*>(out + obase + w));
            }
        }

        if (tn >= tiles) break;
        t = tn; cur ^= 1; i0 = i0n; i1 = i1n;
    }
}

extern "C" void kernel_launch(void* const* d_in, const int* in_sizes, int n_in,
                              void* d_out, int out_size, void* d_ws, size_t ws_size,
                              hipStream_t stream) {
    const float* var_f = (const float*)d_in[0];
    const float* con_f = (const float*)d_in[1];
    const float* Ef    = (const float*)d_in[2];
    const int*   idx   = (const int*)d_in[3];
    const float* Wv1 = (const float*)d_in[4];
    const float* bv1 = (const float*)d_in[5];
    const float* Wv2 = (const float*)d_in[6];
    const float* bv2 = (const float*)d_in[7];
    const float* Wc1 = (const float*)d_in[8];
    const float* bc1 = (const float*)d_in[9];
    const float* Wc2 = (const float*)d_in[10];
    const float* bc2 = (const float*)d_in[11];
    const float* We1 = (const float*)d_in[12];
    const float* be1 = (const float*)d_in[13];
    const float* We2 = (const float*)d_in[14];
    const float* be2 = (const float*)d_in[15];
    float* out = (float*)d_out;

    const int nV = in_sizes[0] / 32;
    const int nC = in_sizes[1] / 32;
    const int nE = in_sizes[2] / 32;

    unsigned short* pv = (unsigned short*)d_ws;
    unsigned short* pc = pv + (size_t)nV * 32;

    // be1 folded into pv (var side); con side gets no bias.
    {
        int ntileV = (nV + 31) >> 5;
        int blocksV = (ntileV * 64 + 255) / 256;
        node_kernel<<<blocksV, 256, 0, stream>>>(var_f, Wv1, bv1, Wv2, bv2,
                                                 We1 + 32, 96, be1, pv, nV);
        int ntileC = (nC + 31) >> 5;
        int blocksC = (ntileC * 64 + 255) / 256;
        node_kernel<<<blocksC, 256, 0, stream>>>(con_f, Wc1, bc1, Wc2, bc2,
                                                 We1 + 64, 96, nullptr, pc, nC);
    }
    edge_kernel<<<1024, 256, 0, stream>>>(Ef, idx, pv, pc, We1, We2, be2, out, nE);
}